// Round 11
// baseline (74.454 us; speedup 1.0000x reference)
//
#include <hip/hip_runtime.h>

// ASTDecoder: batched GCN on fixed banded graph, 2048 graphs x 256 nodes.
// Only 9 distinct rows/graph survive 3 layers (8 boundary + 1 interior).
// History: 102 -> 92 -> 78 -> 73 -> 65.6 -> 66.4 -> 77.9 -> 74.1 -> 64.5us.
// R11 diagnosis (fits every round): all GEMV variants paid ~1 LDS instr per
// FMA; per-CU LDS-issue ~70K cyc ~= 29us on ONE LDS port, and boundary
// waves' LDS stream delayed the interior chain -> stores started ~20us late.
// Fix: GEMVs use NO LDS. Weights -> VGPRs via coalesced global dwords
// (L1/L2-hot); X broadcasts -> v_readlane (VALU pipe, 4 SIMDs parallel).
// LDS only for init split-K reduce (8KB) + O8 f32x4 bounce (2KB); 1 barrier.
// Wave-specialized as R6/R10: interior wave streams 240 nodes ASAP, boundary
// wave computes its 16 nodes under the store drain.

#define NB   2048
#define EMB  256
#define HID  64
#define ODIM 128
#define NN   256
#define MG   4            // graphs per block
#define NBLK (NB / MG)    // 512 blocks x 512 threads = 2 blocks/CU

typedef float f32x4 __attribute__((ext_vector_type(4)));

__device__ __forceinline__ float rl(float v, int k) {
  // broadcast lane k's value (SGPR operand for the FMA)
  return __uint_as_float(__builtin_amdgcn_readlane(__float_as_uint(v), k));
}

__device__ __forceinline__ float dinvf(int j) {
  // deg: node0=3, node1=4, nodes 2..253=5 (mirror symmetric); only j<=9 used.
  if (j == 0) return 0.57735026918962576f;  // 1/sqrt(3)
  if (j == 1) return 0.5f;                  // 1/sqrt(4)
  return 0.44721359549995794f;              // 1/sqrt(5)
}

// One boundary-path GCN layer: chain step + ND row-GEMVs sharing the same
// in-register weight column + banded mix. No LDS, no barriers.
template <int L, int ND>
__device__ __forceinline__ void blayer(float& x8, float (&xb)[8],
                                       const float* __restrict__ convW,
                                       const float* __restrict__ convB, int j) {
  const float* W = convW + L * HID * HID;
  float w[HID];
  #pragma unroll
  for (int k = 0; k < HID; ++k) w[k] = W[k * HID + j];   // coalesced dwords

  float g8 = 0.f;
  #pragma unroll
  for (int k = 0; k < HID; ++k) g8 = fmaf(rl(x8, k), w[k], g8);

  float accR[ND > 0 ? ND : 1] = {};
  if constexpr (ND > 0) {
    #pragma unroll
    for (int r = 0; r < ND; ++r) {
      float a = 0.f;
      #pragma unroll
      for (int k = 0; k < HID; ++k) a = fmaf(rl(xb[r], k), w[k], a);
      accR[r] = a;
    }
  }

  const float cb = convB[L * HID + j];
  constexpr int NDN = (ND + 2 < 4) ? 4 : (ND + 2);
  float xn[NDN];
  #pragma unroll
  for (int i = 0; i < NDN; ++i) {
    const float di = dinvf(i);
    float acc = 0.f;
    #pragma unroll
    for (int jj = (i >= 2 ? i - 2 : 0); jj <= i + 2; ++jj) {
      const float v = (jj < ND) ? accR[jj] : g8;
      acc = fmaf(di * dinvf(jj), v, acc);
    }
    xn[i] = fmaxf(acc + cb, 0.f);
  }
  x8 = fmaxf(g8 + cb, 0.f);
  #pragma unroll
  for (int i = 0; i < NDN; ++i) xb[i] = xn[i];
}

__global__ __launch_bounds__(512, 4) void gcn_fused(
    const float* __restrict__ emb,
    const float* __restrict__ W_emb,
    const float* __restrict__ b_emb,
    const float* __restrict__ convW,
    const float* __restrict__ convB,
    const float* __restrict__ Wout,
    const float* __restrict__ bout,
    float* __restrict__ out)
{
  const int tid   = threadIdx.x;
  const int lane  = tid & 63;
  const int wid   = tid >> 6;          // 0..7
  const int gbase = blockIdx.x * MG;
  const int j     = lane;

  __shared__ float red[8][MG][HID];                 // 8 KB
  __shared__ __align__(16) float O8s[MG][ODIM];     // 2 KB

  // ---- init split-K: wave w owns k-slice [32w,32w+32), all MG graphs ----
  {
    const int k0 = wid * 32;
    float ereg[MG];
    #pragma unroll
    for (int g = 0; g < MG; ++g)
      ereg[g] = emb[(size_t)(gbase + g) * EMB + k0 + (lane & 31)];
    float a[MG] = {};
    #pragma unroll
    for (int kk = 0; kk < 32; ++kk) {
      const float w = W_emb[(k0 + kk) * HID + j];   // coalesced 256B
      #pragma unroll
      for (int g = 0; g < MG; ++g)
        a[g] = fmaf(rl(ereg[g], kk), w, a[g]);
    }
    #pragma unroll
    for (int g = 0; g < MG; ++g) red[wid][g][j] = a[g];
  }
  __syncthreads();   // the only barrier

  const int g = wid & (MG - 1);
  float x8 = b_emb[j];
  #pragma unroll
  for (int w = 0; w < 8; ++w) x8 += red[w][g][j];

  float* og = out + (size_t)(gbase + g) * NN * ODIM;

  if (wid < MG) {
    // ============ interior path (wave g): chain + O8 + 240-node stream ============
    #pragma unroll
    for (int l = 0; l < 3; ++l) {
      const float* W = convW + l * HID * HID;
      float w[HID];
      #pragma unroll
      for (int k = 0; k < HID; ++k) w[k] = W[k * HID + j];
      float acc = 0.f;
      #pragma unroll
      for (int k = 0; k < HID; ++k) acc = fmaf(rl(x8, k), w[k], acc);
      x8 = fmaxf(acc + convB[l * HID + j], 0.f);
    }
    // O8 cols j and j+64 (two passes keep VGPR under the cap)
    #pragma unroll
    for (int c = 0; c < 2; ++c) {
      float w[HID];
      #pragma unroll
      for (int k = 0; k < HID; ++k) w[k] = Wout[k * ODIM + c * 64 + j];
      float acc = bout[c * 64 + j];
      #pragma unroll
      for (int k = 0; k < HID; ++k) acc = fmaf(rl(x8, k), w[k], acc);
      O8s[g][c * 64 + j] = acc;
    }
    // stream interior nodes 8..247 (1 KB per wave-instr, NT: out > L3)
    const int q = lane & 31, half = lane >> 5;
    const f32x4 vint = *reinterpret_cast<const f32x4*>(&O8s[g][q * 4]);
    f32x4* og4 = reinterpret_cast<f32x4*>(og);
    #pragma unroll 8
    for (int it = 0; it < 120; ++it) {
      const int node = 8 + it * 2 + half;
      __builtin_nontemporal_store(vint, &og4[node * 32 + q]);
    }
  } else {
    // ============ boundary path (wave g+4): 8 rows + final + 16 nodes ============
    float xb[8];
    blayer<0, 0>(x8, xb, convW, convB, j);
    blayer<1, 4>(x8, xb, convW, convB, j);
    blayer<2, 6>(x8, xb, convW, convB, j);

    #pragma unroll
    for (int c = 0; c < 2; ++c) {
      float w[HID];
      #pragma unroll
      for (int k = 0; k < HID; ++k) w[k] = Wout[k * ODIM + c * 64 + j];
      const float bo = bout[c * 64 + j];
      float acc[8];
      #pragma unroll
      for (int r = 0; r < 8; ++r) {
        float a = bo;
        #pragma unroll
        for (int k = 0; k < HID; ++k) a = fmaf(rl(xb[r], k), w[k], a);
        acc[r] = a;
      }
      // nodes 0..7 and mirrored 248..255; 256B-coalesced dword NT stores
      #pragma unroll
      for (int n = 0; n < 8; ++n) {
        __builtin_nontemporal_store(acc[n], &og[n * ODIM + c * 64 + j]);
        __builtin_nontemporal_store(acc[n], &og[(255 - n) * ODIM + c * 64 + j]);
      }
    }
  }
}

extern "C" void kernel_launch(void* const* d_in, const int* in_sizes, int n_in,
                              void* d_out, int out_size, void* d_ws, size_t ws_size,
                              hipStream_t stream) {
  const float* emb   = (const float*)d_in[0];
  const float* W_emb = (const float*)d_in[1];
  const float* b_emb = (const float*)d_in[2];
  const float* convW = (const float*)d_in[3];
  const float* convB = (const float*)d_in[4];
  const float* Wout  = (const float*)d_in[5];
  const float* bout  = (const float*)d_in[6];
  float* out = (float*)d_out;

  hipLaunchKernelGGL(gcn_fused, dim3(NBLK), dim3(512), 0, stream,
                     emb, W_emb, b_emb, convW, convB, Wout, bout, out);
}